// Round 1
// baseline (36.254 us; speedup 1.0000x reference)
//
#include <hip/hip_runtime.h>

#define NQ 11
#define NLAYERS 6

// One wave (64 lanes) simulates one sample's 2048-amplitude real statevector.
// Amplitude index i = (r<<6) | lane,  r in [0,32) = per-lane register index.
// Wire w corresponds to bit (10-w) of i (PennyLane MSB-first ordering):
//   wires 0..4  -> r bits 4..0   (in-register butterflies)
//   wires 5..10 -> lane bits 5..0 (__shfl_xor butterflies)

// RY on register bit RB with coeffs (C,S): pairs (r0, r0|1<<RB)
#define RY_REG(RB, C, S)                                                     \
    _Pragma("unroll")                                                        \
    for (int g = 0; g < 16; ++g) {                                           \
        const int r0 = ((g >> (RB)) << ((RB) + 1)) | (g & ((1 << (RB)) - 1));\
        const int r1 = r0 | (1 << (RB));                                     \
        const float a_ = v[r0], b_ = v[r1];                                  \
        v[r0] = (C) * a_ - (S) * b_;                                         \
        v[r1] = (S) * a_ + (C) * b_;                                         \
    }

// CZ on two register bits: compile-time sign flip where both bits set
#define CZ_RR(B1, B2)                                                        \
    _Pragma("unroll")                                                        \
    for (int r = 0; r < 32; ++r)                                             \
        if ((r & (1 << (B1))) && (r & (1 << (B2)))) v[r] = -v[r];

// RY on lane bit (xor MASK): SS is per-lane signed sin (+s if my bit set, -s else)
#define RY_LANE(MASK, C, SS)                                                 \
    _Pragma("unroll")                                                        \
    for (int r = 0; r < 32; ++r) {                                           \
        const float pa_ = __shfl_xor(v[r], (MASK));                          \
        v[r] = (C) * v[r] + (SS) * pa_;                                      \
    }

__global__ __launch_bounds__(256) void qru_kernel(
    const float* __restrict__ x,   // [2048, 16] (only first 11 of last dim used)
    const float* __restrict__ w,   // [11]
    float* __restrict__ out)       // [2048, 11]
{
    const int lane = threadIdx.x & 63;
    const int n    = blockIdx.x * 4 + (threadIdx.x >> 6);  // sample id

    // ---- input-angle and weight half-angle sin/cos ----
    float ci[NQ], si[NQ];
#pragma unroll
    for (int q = 0; q < NQ; ++q) {
        const float h = x[n * 16 + q] * 0.5f;
        __sincosf(h, &si[q], &ci[q]);
    }
    float cw[NQ], sw[NQ];
#pragma unroll
    for (int q = 0; q < NQ; ++q) {
        const float h = w[q] * 0.5f;
        __sincosf(h, &sw[q], &cw[q]);
    }

    // ---- initial product state: amp(i) = prod_w (bit_w(i) ? sin : cos) ----
    // lane bits 5..0 = wires 5..10
    const float laneF =
        ((lane & 32) ? si[5]  : ci[5])  *
        ((lane & 16) ? si[6]  : ci[6])  *
        ((lane & 8)  ? si[7]  : ci[7])  *
        ((lane & 4)  ? si[8]  : ci[8])  *
        ((lane & 2)  ? si[9]  : ci[9])  *
        ((lane & 1)  ? si[10] : ci[10]);

    float v[32];
#pragma unroll
    for (int r = 0; r < 32; ++r) {
        // r bits 4..0 = wires 0..4
        const float f = ((r & 16) ? si[0] : ci[0])
                      * ((r & 8)  ? si[1] : ci[1])
                      * ((r & 4)  ? si[2] : ci[2])
                      * ((r & 2)  ? si[3] : ci[3])
                      * ((r & 1)  ? si[4] : ci[4]);
        v[r] = laneF * f;
    }

    // ---- per-lane constants for lane-involving CZ gates ----
    const float ls5  = (lane & 32) ? -1.f : 1.f;            // lane bit 5 (wire 5)
    const float ls0  = (lane & 1)  ? -1.f : 1.f;            // lane bit 0 (wire 10)
    const float s54  = ((lane & 48) == 48) ? -1.f : 1.f;    // CZ(5,6)
    const float s43  = ((lane & 24) == 24) ? -1.f : 1.f;    // CZ(6,7)
    const float s32_ = ((lane & 12) == 12) ? -1.f : 1.f;    // CZ(7,8)
    const float s21  = ((lane & 6)  == 6)  ? -1.f : 1.f;    // CZ(8,9)
    const float s10  = ((lane & 3)  == 3)  ? -1.f : 1.f;    // CZ(9,10)

    // per-lane signed sin for the lane RY gates (wires 5..10)
    const float ssm32 = (lane & 32) ? sw[5]  : -sw[5];
    const float ssm16 = (lane & 16) ? sw[6]  : -sw[6];
    const float ssm8  = (lane & 8)  ? sw[7]  : -sw[7];
    const float ssm4  = (lane & 4)  ? sw[8]  : -sw[8];
    const float ssm2  = (lane & 2)  ? sw[9]  : -sw[9];
    const float ssm1  = (lane & 1)  ? sw[10] : -sw[10];

    // ---- 6 layers of RY(weights[i]) on wire i, then CZ(i, (i+1)%11) ----
#pragma unroll 1
    for (int l = 0; l < NLAYERS; ++l) {
        RY_REG(4, cw[0], sw[0])         // wire 0
        CZ_RR(4, 3)                     // CZ(0,1)
        RY_REG(3, cw[1], sw[1])         // wire 1
        CZ_RR(3, 2)                     // CZ(1,2)
        RY_REG(2, cw[2], sw[2])         // wire 2
        CZ_RR(2, 1)                     // CZ(2,3)
        RY_REG(1, cw[3], sw[3])         // wire 3
        CZ_RR(1, 0)                     // CZ(3,4)
        RY_REG(0, cw[4], sw[4])         // wire 4
#pragma unroll
        for (int r = 1; r < 32; r += 2) v[r] *= ls5;   // CZ(4,5): r bit0 & lane bit5
        RY_LANE(32, cw[5], ssm32)       // wire 5
#pragma unroll
        for (int r = 0; r < 32; ++r) v[r] *= s54;      // CZ(5,6)
        RY_LANE(16, cw[6], ssm16)       // wire 6
#pragma unroll
        for (int r = 0; r < 32; ++r) v[r] *= s43;      // CZ(6,7)
        RY_LANE(8, cw[7], ssm8)         // wire 7
#pragma unroll
        for (int r = 0; r < 32; ++r) v[r] *= s32_;     // CZ(7,8)
        RY_LANE(4, cw[8], ssm4)         // wire 8
#pragma unroll
        for (int r = 0; r < 32; ++r) v[r] *= s21;      // CZ(8,9)
        RY_LANE(2, cw[9], ssm2)         // wire 9
#pragma unroll
        for (int r = 0; r < 32; ++r) v[r] *= s10;      // CZ(9,10)
        RY_LANE(1, cw[10], ssm1)        // wire 10
#pragma unroll
        for (int r = 16; r < 32; ++r) v[r] *= ls0;     // CZ(10,0): r bit4 & lane bit0
    }

    // ---- measurement: out[w] = sum_i |amp_i|^2 * (1 - 2*bit_w(i)) ----
    float p[32];
#pragma unroll
    for (int r = 0; r < 32; ++r) p[r] = v[r] * v[r];

    float tot = 0.f;
#pragma unroll
    for (int r = 0; r < 32; ++r) tot += p[r];

    float S4 = 0.f, S3 = 0.f, S2 = 0.f, S1 = 0.f, S0 = 0.f;
#pragma unroll
    for (int r = 0; r < 32; ++r) {
        if (r & 16) S4 += p[r];
        if (r & 8)  S3 += p[r];
        if (r & 4)  S2 += p[r];
        if (r & 2)  S1 += p[r];
        if (r & 1)  S0 += p[r];
    }

    float q[NQ];
    q[0] = tot - 2.f * S4;              // wire 0 (r bit 4)
    q[1] = tot - 2.f * S3;
    q[2] = tot - 2.f * S2;
    q[3] = tot - 2.f * S1;
    q[4] = tot - 2.f * S0;
    q[5]  = (lane & 32) ? -tot : tot;   // wire 5 (lane bit 5)
    q[6]  = (lane & 16) ? -tot : tot;
    q[7]  = (lane & 8)  ? -tot : tot;
    q[8]  = (lane & 4)  ? -tot : tot;
    q[9]  = (lane & 2)  ? -tot : tot;
    q[10] = (lane & 1)  ? -tot : tot;

#pragma unroll
    for (int wq = 0; wq < NQ; ++wq) {
        float a = q[wq];
        a += __shfl_xor(a, 32);
        a += __shfl_xor(a, 16);
        a += __shfl_xor(a, 8);
        a += __shfl_xor(a, 4);
        a += __shfl_xor(a, 2);
        a += __shfl_xor(a, 1);
        q[wq] = a;
    }

    if (lane == 0) {
#pragma unroll
        for (int wq = 0; wq < NQ; ++wq) out[n * 11 + wq] = q[wq];
    }
}

extern "C" void kernel_launch(void* const* d_in, const int* in_sizes, int n_in,
                              void* d_out, int out_size, void* d_ws, size_t ws_size,
                              hipStream_t stream) {
    const float* x = (const float*)d_in[0];   // [8,256,16] f32
    const float* w = (const float*)d_in[1];   // [11] f32
    float* out = (float*)d_out;               // [8,256,11] f32

    // 2048 samples, 1 wave each, 4 waves per block -> 512 blocks
    qru_kernel<<<512, 256, 0, stream>>>(x, w, out);
}